// Round 3
// baseline (94.891 us; speedup 1.0000x reference)
//
#include <hip/hip_runtime.h>
#include <math.h>

// RecurrentNALU single step, fp32. B=4096, IN=128, HID=128, CAT=256.
// R3: single kernel. Weight loads forced into the VECTOR (vmcnt) domain via an
// opaque VGPR zero so ds_read (lgkmcnt) and global loads (vmcnt) pipeline
// independently; b128 LDS x-reads via c-quad-major swizzled layout; packed
// clamps in-loop (preclamp kernel dropped).

#define BATCH    4096
#define HID      128
#define CAT      256
#define BR       64              // rows per block
#define CHUNK    64              // c per staged chunk
#define NCHUNK   (CAT / CHUNK)   // 4
#define CPW      2               // cols (h) per wave
#define NWAVES   4
#define CPB      (CPW * NWAVES)  // 8 cols per block
#define COLB     (HID / CPB)     // 16 column blocks
#define GRID     ((BATCH / BR) * COLB) // 1024

typedef float f32x2 __attribute__((ext_vector_type(2)));
typedef float f32x4 __attribute__((ext_vector_type(4)));

static __device__ __forceinline__ f32x2 pk_fma(f32x2 a, f32x2 b, f32x2 c) {
#if __has_builtin(__builtin_elementwise_fma)
    return __builtin_elementwise_fma(a, b, c);
#else
    f32x2 r; r.x = fmaf(a.x, b.x, c.x); r.y = fmaf(a.y, b.y, c.y); return r;
#endif
}
static __device__ __forceinline__ f32x4 clamp4(f32x4 v, float lo, float hi) {
#if __has_builtin(__builtin_elementwise_min) && __has_builtin(__builtin_elementwise_max)
    return __builtin_elementwise_min(
               __builtin_elementwise_max(v, (f32x4){lo, lo, lo, lo}),
               (f32x4){hi, hi, hi, hi});
#else
    f32x4 r;
    r.x = fminf(fmaxf(v.x, lo), hi); r.y = fminf(fmaxf(v.y, lo), hi);
    r.z = fminf(fmaxf(v.z, lo), hi); r.w = fminf(fmaxf(v.w, lo), hi);
    return r;
#endif
}

__global__ __launch_bounds__(256, 4)
void nalu_step_kernel(const float* __restrict__ x_t,
                      const float* __restrict__ h_tm1,
                      const float* __restrict__ Wa_,
                      const float* __restrict__ Wm_,
                      const float* __restrict__ Ga_,
                      float* __restrict__ out)
{
    // c-quad-major: float index = t*256 + ((r ^ t)<<2) + k, t = c-quad (0..15),
    // r = row slot. Bank-balanced for b128 staging writes AND b128 compute reads.
    __shared__ float xs[2][CHUNK * BR]; // 2 x 16 KB

    // XCD-bijective swizzle (GRID % 8 == 0)
    const int bid = blockIdx.x;
    const int cpx = GRID >> 3;
    const int wg  = (bid & 7) * cpx + (bid >> 3);
    const int rowBlk  = wg / COLB;
    const int colBlk  = wg % COLB;
    const int rowBase = rowBlk * BR;

    const int tid  = threadIdx.x;
    const int lane = tid & 63;
    const int wave = __builtin_amdgcn_readfirstlane(tid >> 6);
    const int hBase = colBlk * CPB + wave * CPW;

    // Opaque VGPR zero: forces weight loads to be VECTOR global loads (vmcnt),
    // keeping them out of the lgkmcnt domain shared with ds_read.
    int zero;
    asm("v_mov_b32 %0, 0" : "=v"(zero));

    // Per-stream divergent-looking base pointers; all per-load offsets fit the
    // 13-bit immediate (max (CPW-1)*CAT + 3*CHUNK + 60 floats = ~2 KB).
    const float* __restrict__ pW = Wa_ + (size_t)hBase * CAT + zero;
    const float* __restrict__ pM = Wm_ + (size_t)hBase * CAT + zero;
    const float* __restrict__ pG = Ga_ + (size_t)hBase * CAT + zero;

#define STAGE(CH, BUF)                                                         \
    do {                                                                       \
        const float* __restrict__ sbase = ((CH) < 2) ? x_t : h_tm1;            \
        const int colOff = ((CH) & 1) * 64;                                    \
        _Pragma("unroll")                                                      \
        for (int it = 0; it < 4; ++it) {                                       \
            const int idx4 = tid + it * 256;                                   \
            const int r = idx4 >> 4;                                           \
            const int u = idx4 & 15;                                           \
            const f32x4 v = *reinterpret_cast<const f32x4*>(                   \
                sbase + (size_t)(rowBase + r) * 128 + colOff + u * 4);         \
            *reinterpret_cast<f32x4*>(&xs[BUF][u * 256 + ((r ^ u) << 2)]) = v; \
        }                                                                      \
    } while (0)

    // split accumulators (even/odd quad halves) for ILP
    f32x2 aa[CPW][2], ag[CPW][2], am[CPW][2];
    #pragma unroll
    for (int j = 0; j < CPW; ++j) {
        aa[j][0] = (f32x2){0.f, 0.f}; aa[j][1] = (f32x2){0.f, 0.f};
        ag[j][0] = (f32x2){0.f, 0.f}; ag[j][1] = (f32x2){0.f, 0.f};
        am[j][0] = (f32x2){1.f, 1.f}; am[j][1] = (f32x2){1.f, 1.f};
    }

    STAGE(0, 0);
    __syncthreads();

    #pragma unroll
    for (int ch = 0; ch < NCHUNK; ++ch) {
        const int cur = ch & 1;
        if (ch == 0) STAGE(1, 1);
        if (ch == 1) STAGE(2, 0);
        if (ch == 2) STAGE(3, 1);

        #pragma unroll 4
        for (int t = 0; t < CHUNK / 4; ++t) {
            const f32x4 xv = *reinterpret_cast<const f32x4*>(
                &xs[cur][t * 256 + ((lane ^ t) << 2)]);
            const f32x2 xlo = {xv.x, xv.y};
            const f32x2 xhi = {xv.z, xv.w};
            const f32x2 mlo = xlo - 1.0f;
            const f32x2 mhi = xhi - 1.0f;
            #pragma unroll
            for (int j = 0; j < CPW; ++j) {
                const int off = j * CAT + ch * CHUNK + 4 * t;
                f32x4 wa = *reinterpret_cast<const f32x4*>(pW + off);
                f32x4 wm = *reinterpret_cast<const f32x4*>(pM + off);
                const f32x4 gv = *reinterpret_cast<const f32x4*>(pG + off);
                wa = clamp4(wa, -1.f, 1.f);
                wm = clamp4(wm,  0.f, 1.f);
                aa[j][0] = pk_fma(xlo, (f32x2){wa.x, wa.y}, aa[j][0]);
                aa[j][1] = pk_fma(xhi, (f32x2){wa.z, wa.w}, aa[j][1]);
                ag[j][0] = pk_fma(xlo, (f32x2){gv.x, gv.y}, ag[j][0]);
                ag[j][1] = pk_fma(xhi, (f32x2){gv.z, gv.w}, ag[j][1]);
                am[j][0] = am[j][0] * pk_fma((f32x2){wm.x, wm.y}, mlo, (f32x2){1.f, 1.f});
                am[j][1] = am[j][1] * pk_fma((f32x2){wm.z, wm.w}, mhi, (f32x2){1.f, 1.f});
            }
        }
        __syncthreads();
    }
#undef STAGE

    // ---- epilogue: sigmoid gate + blend, float2 store ----
    const int r = rowBase + lane;
    float2 o;
    {
        const f32x2 sa = aa[0][0] + aa[0][1];
        const f32x2 sz = ag[0][0] + ag[0][1];
        const f32x2 sm = am[0][0] * am[0][1];
        const float a = sa.x + sa.y, z = sz.x + sz.y, m = sm.x * sm.y;
        const float g = 1.0f / (1.0f + __expf(-z));
        o.x = g * a + (1.0f - g) * m;
    }
    {
        const f32x2 sa = aa[1][0] + aa[1][1];
        const f32x2 sz = ag[1][0] + ag[1][1];
        const f32x2 sm = am[1][0] * am[1][1];
        const float a = sa.x + sa.y, z = sz.x + sz.y, m = sm.x * sm.y;
        const float g = 1.0f / (1.0f + __expf(-z));
        o.y = g * a + (1.0f - g) * m;
    }
    *reinterpret_cast<float2*>(out + (size_t)r * HID + hBase) = o;
}

extern "C" void kernel_launch(void* const* d_in, const int* in_sizes, int n_in,
                              void* d_out, int out_size, void* d_ws, size_t ws_size,
                              hipStream_t stream)
{
    const float* x_t   = (const float*)d_in[0];
    const float* h_tm1 = (const float*)d_in[1];
    const float* W_add = (const float*)d_in[2];
    const float* W_mul = (const float*)d_in[3];
    const float* G_add = (const float*)d_in[4];
    float* out = (float*)d_out;

    nalu_step_kernel<<<GRID, 256, 0, stream>>>(x_t, h_tm1, W_add, W_mul, G_add, out);
}

// Round 4
// 50.245 us; speedup vs baseline: 1.8886x; 1.8886x over previous
//
#include <hip/hip_runtime.h>
#include <math.h>

// RecurrentNALU single step, fp32. B=4096, IN=128, HID=128, CAT=256.
// R4: lane = output column h (weights become per-lane vector loads in native
// [h][c] layout, vmcnt domain, immediate offsets). x staged row-major in LDS,
// read as uniform-address ds_read_b128 broadcasts. No barrier in main loop.
// Block: 512 thr = 8 waves = (h-half, row-quarter); 4 rows x 64 h per wave.
// Grid: 256 blocks x 16 rows = exactly 1 block per CU.

#define BATCH 4096
#define HID   128
#define CAT   256
#define ROWS  16            // rows per block
#define RPW   4             // rows per wave
#define GRID  (BATCH / ROWS) // 256

typedef float f32x2 __attribute__((ext_vector_type(2)));
typedef float f32x4 __attribute__((ext_vector_type(4)));

static __device__ __forceinline__ f32x2 pk_fma(f32x2 a, f32x2 b, f32x2 c) {
#if __has_builtin(__builtin_elementwise_fma)
    return __builtin_elementwise_fma(a, b, c);
#else
    f32x2 r; r.x = fmaf(a.x, b.x, c.x); r.y = fmaf(a.y, b.y, c.y); return r;
#endif
}
static __device__ __forceinline__ f32x4 clamp4(f32x4 v, float lo, float hi) {
#if __has_builtin(__builtin_elementwise_min) && __has_builtin(__builtin_elementwise_max)
    return __builtin_elementwise_min(
               __builtin_elementwise_max(v, (f32x4){lo, lo, lo, lo}),
               (f32x4){hi, hi, hi, hi});
#else
    f32x4 r;
    r.x = fminf(fmaxf(v.x, lo), hi); r.y = fminf(fmaxf(v.y, lo), hi);
    r.z = fminf(fmaxf(v.z, lo), hi); r.w = fminf(fmaxf(v.w, lo), hi);
    return r;
#endif
}

__global__ __launch_bounds__(512, 2)
void nalu_step_kernel(const float* __restrict__ x_t,
                      const float* __restrict__ h_tm1,
                      const float* __restrict__ Wa_,
                      const float* __restrict__ Wm_,
                      const float* __restrict__ Ga_,
                      float* __restrict__ out)
{
    __shared__ float xs[ROWS][CAT]; // 16 KB, row-major, no swizzle (uniform reads)

    const int tid = threadIdx.x;
    const int rowBase = blockIdx.x * ROWS;

    // ---- stage x = concat(x_t, h_tm1) row-major; fully coalesced ----
    #pragma unroll
    for (int it = 0; it < 2; ++it) {
        const int idx4 = tid + it * 512;  // 0..1023 float4 slots
        const int r  = idx4 >> 6;         // 16 rows x 64 float4/row
        const int c4 = idx4 & 63;
        const float* src = (c4 < 32)
            ? (x_t   + (size_t)(rowBase + r) * 128 + c4 * 4)
            : (h_tm1 + (size_t)(rowBase + r) * 128 + (c4 - 32) * 4);
        *reinterpret_cast<f32x4*>(&xs[r][c4 * 4]) =
            *reinterpret_cast<const f32x4*>(src);
    }
    __syncthreads();

    const int lane = tid & 63;
    const int wid  = __builtin_amdgcn_readfirstlane(tid >> 6); // 0..7
    const int h0   = (wid & 1) * 64 + lane;   // output column owned by this lane
    const int r0   = (wid >> 1) * RPW;        // first of 4 rows (scalar)

    // Per-lane weight row bases; all 64 quad-loads use 13-bit imm offsets.
    const float* __restrict__ pA = Wa_ + (size_t)h0 * CAT;
    const float* __restrict__ pM = Wm_ + (size_t)h0 * CAT;
    const float* __restrict__ pG = Ga_ + (size_t)h0 * CAT;

    f32x2 aa[RPW], ag[RPW], am[RPW];
    #pragma unroll
    for (int r = 0; r < RPW; ++r) {
        aa[r] = (f32x2){0.f, 0.f};
        ag[r] = (f32x2){0.f, 0.f};
        am[r] = (f32x2){1.f, 1.f};
    }

    // ---- main loop: 64 c-quads, no barriers ----
    #pragma unroll 4
    for (int cq = 0; cq < CAT / 4; ++cq) {
        f32x4 wa = *reinterpret_cast<const f32x4*>(pA + cq * 4);
        f32x4 wm = *reinterpret_cast<const f32x4*>(pM + cq * 4);
        const f32x4 ga = *reinterpret_cast<const f32x4*>(pG + cq * 4);
        wa = clamp4(wa, -1.f, 1.f);
        wm = clamp4(wm,  0.f, 1.f);
        const f32x2 walo = {wa.x, wa.y}, wahi = {wa.z, wa.w};
        const f32x2 wmlo = {wm.x, wm.y}, wmhi = {wm.z, wm.w};
        const f32x2 galo = {ga.x, ga.y}, gahi = {ga.z, ga.w};

        #pragma unroll
        for (int r = 0; r < RPW; ++r) {
            // uniform-address broadcast read, conflict-free
            const f32x4 xv = *reinterpret_cast<const f32x4*>(&xs[r0 + r][cq * 4]);
            const f32x2 xlo = {xv.x, xv.y}, xhi = {xv.z, xv.w};
            aa[r] = pk_fma(xlo, walo, aa[r]);
            aa[r] = pk_fma(xhi, wahi, aa[r]);
            ag[r] = pk_fma(xlo, galo, ag[r]);
            ag[r] = pk_fma(xhi, gahi, ag[r]);
            const f32x2 one = {1.f, 1.f};
            const f32x2 t0 = pk_fma(wmlo, xlo - one, one);
            const f32x2 t1 = pk_fma(wmhi, xhi - one, one);
            am[r] = am[r] * t0;
            am[r] = am[r] * t1;
        }
    }

    // ---- epilogue: sigmoid gate + blend; coalesced scalar stores ----
    #pragma unroll
    for (int r = 0; r < RPW; ++r) {
        const float a = aa[r].x + aa[r].y;
        const float z = ag[r].x + ag[r].y;
        const float m = am[r].x * am[r].y;
        const float g = 1.0f / (1.0f + __expf(-z));
        out[(size_t)(rowBase + r0 + r) * HID + h0] = g * a + (1.0f - g) * m;
    }
}

extern "C" void kernel_launch(void* const* d_in, const int* in_sizes, int n_in,
                              void* d_out, int out_size, void* d_ws, size_t ws_size,
                              hipStream_t stream)
{
    const float* x_t   = (const float*)d_in[0];
    const float* h_tm1 = (const float*)d_in[1];
    const float* W_add = (const float*)d_in[2];
    const float* W_mul = (const float*)d_in[3];
    const float* G_add = (const float*)d_in[4];
    float* out = (float*)d_out;

    nalu_step_kernel<<<GRID, 512, 0, stream>>>(x_t, h_tm1, W_add, W_mul, G_add, out);
}